// Round 9
// baseline (188.311 us; speedup 1.0000x reference)
//
#include <hip/hip_runtime.h>
#include <hip/hip_bf16.h>
#include <math.h>

// Delta-rule linear attention, chunked + MFMA bf16, bf16 state buffer.
// B=8, S=4096, D=256, L=128 -> C=32 chunks/batch, 256 chunks total.
// R9: front kernel dumps V^T bf16 to global (Vt) so the output kernel needs
// NO V staging (A-op frags straight from global) -> 2 barriers, leaner LDS.
// ws: A/H [256][256][256] bf16 [j][i] (33.5 MB) + P [256] f32 + Vt
//     [256][256 j][128 s] bf16 (16.7 MB).

#define B_ 8
#define S_ 4096
#define D_ 256
#define L_ 128
#define C_ (S_ / L_)      // 32
#define BC_ (B_ * C_)     // 256

typedef __attribute__((ext_vector_type(8))) short s8v;   // 8 bf16 (4 VGPR)
typedef __attribute__((ext_vector_type(4))) float f4v;   // MFMA acc
typedef unsigned short u16;
typedef unsigned int u32;

__device__ __forceinline__ u32 pk2(float lo, float hi) {  // v_cvt_pk_bf16_f32
  union { __hip_bfloat162 h; u32 u; } cv;
  cv.h = __float22bfloat162_rn(make_float2(lo, hi));
  return cv.u;
}
__device__ __forceinline__ s8v pack8(const float4 a, const float4 b) {
  union { u32 u[4]; s8v v; } r;
  r.u[0] = pk2(a.x, a.y); r.u[1] = pk2(a.z, a.w);
  r.u[2] = pk2(b.x, b.y); r.u[3] = pk2(b.z, b.w);
  return r.v;
}

// 128-step prefix log2(beta) scan by wave 0 into ls[].
__device__ __forceinline__ void beta_scan128(const float* betap, float* ls,
                                             int tid) {
  if (tid < 64) {
    float x = log2f(fmaxf(betap[tid], 1e-30f));
#pragma unroll
    for (int off = 1; off < 64; off <<= 1) {
      float y = __shfl_up(x, off);
      if (tid >= off) x += y;
    }
    ls[tid] = x;
    const float tot0 = __shfl(x, 63);
    float z = log2f(fmaxf(betap[64 + tid], 1e-30f));
#pragma unroll
    for (int off = 1; off < 64; off <<= 1) {
      float y = __shfl_up(z, off);
      if (tid >= off) z += y;
    }
    ls[64 + tid] = z + tot0;
  }
}

// ---------------------------------------------------------------------------
// Kernel 1 (front): A[bc][j][i] = sum_s w_s k_s[i] v_s[j]  (bf16, [j][i]);
// P[bc] = prod beta; ALSO dumps V^T bf16 -> Vt[bc][j][s] for the output
// kernel.  1024 thr / 16 waves, ~102 KB LDS, 1 block/CU.
// ---------------------------------------------------------------------------
__global__ __launch_bounds__(1024, 1) void ks_front9(
    const float* __restrict__ kg, const float* __restrict__ vg,
    const float* __restrict__ beta, u16* __restrict__ A,
    float* __restrict__ P, u16* __restrict__ Vt)
{
  __shared__ float ls[L_];
  __shared__ __align__(16) u16 U[2][256 * 66];   // K^T halves, then V^T halves
  __shared__ __align__(16) u16 BN[64 * 264];     // bounce [64 j][264 i-pad]

  const int bc = blockIdx.x;
  const int b = bc / C_, c = bc % C_;
  const int tid = threadIdx.x;
  const float* betap = beta + (size_t)b * S_ + (size_t)c * L_;
  const float* kbase = kg + ((size_t)b * S_ + (size_t)c * L_) * D_;
  const float* vbase = vg + ((size_t)b * S_ + (size_t)c * L_) * D_;

  beta_scan128(betap, ls, tid);
  __syncthreads();
  const float ltot = ls[L_ - 1];
  if (tid == 0) P[bc] = exp2f(ltot);

  const int hh = tid >> 9;            // s-half this thread stages
  const int t2 = tid & 511;
  const int iLs = t2 & 15;
  const int s0s = (t2 >> 4) * 2;      // local s-pair 0..62
  const int sg = hh * 64 + s0s;

  // ---- stage w-scaled K^T (both halves at once) ----
  {
    const float* src0 = kbase + (size_t)sg * D_;
    const float* src1 = src0 + D_;
    const float w0 = exp2f(ltot - ls[sg]);
    const float w1 = exp2f(ltot - ls[sg + 1]);
    u16* dst = U[hh];
#pragma unroll
    for (int p = 0; p < 4; ++p) {
      const int i0 = p * 64 + iLs * 4;
      float a0[4], a1[4];
      *(float4*)a0 = *(const float4*)(src0 + i0);
      *(float4*)a1 = *(const float4*)(src1 + i0);
#pragma unroll
      for (int u = 0; u < 4; ++u)
        *(u32*)&dst[(i0 + u) * 66 + s0s] = pk2(a0[u] * w0, a1[u] * w1);
    }
  }
  __syncthreads();

  const int lane = tid & 63, wave = tid >> 6;
  const int quad = lane >> 4, l15 = lane & 15;
  const int i0w = wave * 16;          // 16-i strip for this wave

  // cache A-operand (K^T) fragments covering all 4 k-steps (s=128)
  s8v af[4];
#pragma unroll
  for (int ks = 0; ks < 4; ++ks)
    af[ks] = *(const s8v*)&U[ks >> 1][(i0w + l15) * 66 +
                                      (ks & 1) * 32 + quad * 8];
  __syncthreads();

  // ---- stage V^T over K^T's LDS ----
  {
    const float* src0 = vbase + (size_t)sg * D_;
    const float* src1 = src0 + D_;
    u16* dst = U[hh];
#pragma unroll
    for (int p = 0; p < 4; ++p) {
      const int i0 = p * 64 + iLs * 4;
      float a0[4], a1[4];
      *(float4*)a0 = *(const float4*)(src0 + i0);
      *(float4*)a1 = *(const float4*)(src1 + i0);
#pragma unroll
      for (int u = 0; u < 4; ++u)
        *(u32*)&dst[(i0 + u) * 66 + s0s] = pk2(a0[u], a1[u]);
    }
  }
  __syncthreads();

  // ---- dump V^T -> global Vt[bc][j][s] (coalesced; overlaps with MFMA) ----
  {
    u16* Vtb = Vt + (size_t)bc * (D_ * L_);
    const int j = tid >> 2;           // 0..255
    const int qq = tid & 3;           // s-quarter (32 s)
    const u16* srcl = &U[qq >> 1][j * 66 + (qq & 1) * 32];
    u16* dst = Vtb + (size_t)j * L_ + qq * 32;
#pragma unroll
    for (int p = 0; p < 4; ++p)
      *(s8v*)(dst + p * 8) = *(const s8v*)(srcl + p * 8);
  }

  u16* Ab = A + (size_t)bc * D_ * D_;

  for (int ng = 0; ng < 4; ++ng) {    // j-groups of 64
    f4v acc[4];
#pragma unroll
    for (int nt = 0; nt < 4; ++nt) acc[nt] = (f4v){0.f, 0.f, 0.f, 0.f};

#pragma unroll
    for (int ks = 0; ks < 4; ++ks) {
      const int so = (ks & 1) * 32 + quad * 8;
      s8v bv[4];
#pragma unroll
      for (int nt = 0; nt < 4; ++nt)
        bv[nt] = *(const s8v*)&U[ks >> 1][(ng * 64 + nt * 16 + l15) * 66 + so];
#pragma unroll
      for (int nt = 0; nt < 4; ++nt)
        acc[nt] = __builtin_amdgcn_mfma_f32_16x16x32_bf16(
            af[ks], bv[nt], acc[nt], 0, 0, 0);
    }
    // C-frags -> bounce (r runs along i: in-lane packing)
#pragma unroll
    for (int nt = 0; nt < 4; ++nt) {
      const int jl = nt * 16 + l15;
      uint2 w;
      w.x = pk2(acc[nt][0], acc[nt][1]);
      w.y = pk2(acc[nt][2], acc[nt][3]);
      *(uint2*)&BN[jl * 264 + i0w + quad * 4] = w;
    }
    __syncthreads();
    // coalesced copy-out: 64 rows x 512 B
    {
      const int jl = tid >> 4;
      const int il = (tid & 15) * 8;
#pragma unroll
      for (int p = 0; p < 2; ++p) {
        const int iu = il + p * 128;
        *(s8v*)&Ab[(size_t)(ng * 64 + jl) * D_ + iu] =
            *(const s8v*)&BN[jl * 264 + iu];
      }
    }
    __syncthreads();
  }
}

// ---------------------------------------------------------------------------
// Kernel 2: register-batched chunk scan (unchanged).
// ---------------------------------------------------------------------------
__global__ __launch_bounds__(256) void ks_scan9(
    u16* __restrict__ A, const float* __restrict__ P)
{
  const int g = blockIdx.x;                       // 512 blocks
  const int b = g >> 6;                           // 64 blocks / batch
  const int unit = ((g & 63) << 8) + threadIdx.x; // uint2 unit 0..16383
  u16* base = A + (size_t)b * ((size_t)C_ * D_ * D_) + (size_t)unit * 4;
  const float* Pb = P + b * C_;

  uint2 d[C_];
#pragma unroll
  for (int c = 0; c < C_; ++c)
    d[c] = *(const uint2*)(base + (size_t)c * (D_ * D_));

  float h0 = 0.f, h1 = 0.f, h2 = 0.f, h3 = 0.f;
#pragma unroll
  for (int c = 0; c < C_; ++c) {
    const float pc = Pb[c];
    const uint2 u = d[c];
    const float a0 = __uint_as_float(u.x << 16);
    const float a1 = __uint_as_float(u.x & 0xFFFF0000u);
    const float a2 = __uint_as_float(u.y << 16);
    const float a3 = __uint_as_float(u.y & 0xFFFF0000u);
    d[c].x = pk2(h0, h1);
    d[c].y = pk2(h2, h3);
    h0 = fmaf(pc, h0, a0); h1 = fmaf(pc, h1, a1);
    h2 = fmaf(pc, h2, a2); h3 = fmaf(pc, h3, a3);
  }
#pragma unroll
  for (int c = 0; c < C_; ++c)
    *(uint2*)(base + (size_t)c * (D_ * D_)) = d[c];
}

// ---------------------------------------------------------------------------
// Kernel 3: O = Tm @ V + diag(c) Q @ H.  1024 thr / 16 waves, ~101 KB LDS.
// All A-op frags (H x8, Vt x4) issued from global BEFORE barrier 1; consumed
// after barrier 2.  Phases: [beta | QB stage | A-frag issue] -> sync ->
// phase A (K global) writes Tm -> sync -> QH + TmV MFMA burst -> epilogue.
// ---------------------------------------------------------------------------
__global__ __launch_bounds__(1024, 1) void ks_output9(
    const float* __restrict__ qg, const float* __restrict__ kg,
    const float* __restrict__ beta, const u16* __restrict__ Hg,
    const u16* __restrict__ Vt, float* __restrict__ outg)
{
  __shared__ float ls[L_];
  __shared__ float cv[L_];
  __shared__ __align__(16) u16 QB[L_ * 264];     // [t][d] bf16   (67.6 KB)
  __shared__ __align__(16) u16 Tm[L_ * 136];     // [t][s] bf16   (34.8 KB)

  const int bc = blockIdx.x;
  const int b = bc / C_, c = bc % C_;
  const int tid = threadIdx.x;
  const float* betap = beta + (size_t)b * S_ + (size_t)c * L_;
  const float* qbase = qg + ((size_t)b * S_ + (size_t)c * L_) * D_;
  const float* kbase = kg + ((size_t)b * S_ + (size_t)c * L_) * D_;
  const u16* Hb = Hg + (size_t)bc * D_ * D_;
  const u16* Vtb = Vt + (size_t)bc * (D_ * L_);

  beta_scan128(betap, ls, tid);

  // ---- stage QB row-major bf16 ----
  {
    const int t = tid >> 3;
    const int d8 = (tid & 7) * 8;
    const float* src = qbase + (size_t)t * D_;
#pragma unroll
    for (int p = 0; p < 4; ++p) {
      const int d0 = d8 + p * 64;
      const s8v pk = pack8(*(const float4*)(src + d0),
                           *(const float4*)(src + d0 + 4));
      *(s8v*)&QB[t * 264 + d0] = pk;
    }
  }

  const int lane = tid & 63, wave = tid >> 6;
  const int quad = lane >> 4, l15 = lane & 15;
  const int j0w = wave * 16;

  // ---- issue ALL A-op frags for this wave's j-strip (consumed later) ----
  s8v hfr[8], vfr[4];
#pragma unroll
  for (int ks = 0; ks < 8; ++ks)
    hfr[ks] = *(const s8v*)(Hb + (size_t)(j0w + l15) * D_ + ks * 32 + quad * 8);
#pragma unroll
  for (int ks = 0; ks < 4; ++ks)
    vfr[ks] = *(const s8v*)(Vtb + (size_t)(j0w + l15) * L_ + ks * 32 + quad * 8);

  __syncthreads();
  if (tid < L_) cv[tid] = exp2f(ls[tid]);   // c_t (read after next sync)

  // ---- phase A: T = Q K^T.  wave: s-tile (w&7), t-group (w>>3)*64 ----
  {
    const int mA = (wave & 7) * 16;     // s-tile base
    const int tg = (wave >> 3) * 64;    // t-group base
    f4v accA[4];
#pragma unroll
    for (int i = 0; i < 4; ++i) accA[i] = (f4v){0.f, 0.f, 0.f, 0.f};
#pragma unroll
    for (int kd = 0; kd < 8; ++kd) {
      const int d0 = kd * 32 + quad * 8;
      const float* krow = kbase + (size_t)(mA + l15) * D_ + d0;
      const s8v afr = pack8(*(const float4*)krow, *(const float4*)(krow + 4));
#pragma unroll
      for (int nt = 0; nt < 4; ++nt) {
        const s8v bf = *(const s8v*)&QB[(tg + nt * 16 + l15) * 264 + d0];
        accA[nt] = __builtin_amdgcn_mfma_f32_16x16x32_bf16(afr, bf, accA[nt],
                                                           0, 0, 0);
      }
    }
    // rows = s (quad*4+r), cols = t (l15): mask+decay, pack s-pairs
#pragma unroll
    for (int nt = 0; nt < 4; ++nt) {
      const int t = tg + nt * 16 + l15;
      const float lt = ls[t];
      const int s0 = mA + quad * 4;
      float v[4];
#pragma unroll
      for (int r = 0; r < 4; ++r) {
        const int s = s0 + r;
        v[r] = (s <= t) ? accA[nt][r] * exp2f(lt - ls[s]) : 0.f;
      }
      uint2 w;
      w.x = pk2(v[0], v[1]);
      w.y = pk2(v[2], v[3]);
      *(uint2*)&Tm[t * 136 + s0] = w;
    }
  }
  __syncthreads();   // Tm ready

  // ---- Q @ H (A-op = hfr, B-op = QB) ----
  f4v acc[8];
#pragma unroll
  for (int nt = 0; nt < 8; ++nt) acc[nt] = (f4v){0.f, 0.f, 0.f, 0.f};

#pragma unroll
  for (int ks = 0; ks < 8; ++ks) {
    const int io = ks * 32 + quad * 8;
    s8v bf[8];
#pragma unroll
    for (int nt = 0; nt < 8; ++nt)
      bf[nt] = *(const s8v*)&QB[(nt * 16 + l15) * 264 + io];
#pragma unroll
    for (int nt = 0; nt < 8; ++nt)
      acc[nt] = __builtin_amdgcn_mfma_f32_16x16x32_bf16(hfr[ks], bf[nt],
                                                        acc[nt], 0, 0, 0);
  }
  // scale by c_t  (t = nt*16 + l15 constant per lane per nt)
#pragma unroll
  for (int nt = 0; nt < 8; ++nt) {
    const float ct = cv[nt * 16 + l15];
    acc[nt][0] *= ct; acc[nt][1] *= ct;
    acc[nt][2] *= ct; acc[nt][3] *= ct;
  }

  // ---- Tm @ V (A-op = vfr, B-op = Tm) ----
#pragma unroll
  for (int ks = 0; ks < 4; ++ks) {
    const int so = ks * 32 + quad * 8;
    s8v bf[8];
#pragma unroll
    for (int nt = 0; nt < 8; ++nt)
      bf[nt] = *(const s8v*)&Tm[(nt * 16 + l15) * 136 + so];
#pragma unroll
    for (int nt = 0; nt < 8; ++nt)
      acc[nt] = __builtin_amdgcn_mfma_f32_16x16x32_bf16(vfr[ks], bf[nt],
                                                        acc[nt], 0, 0, 0);
  }

  // ---- epilogue: float4 stores (r runs along j) ----
  float* ob = outg + ((size_t)b * S_ + (size_t)c * L_) * D_;
#pragma unroll
  for (int nt = 0; nt < 8; ++nt) {
    const int t = nt * 16 + l15;
    const int j0 = j0w + quad * 4;
    float4 o;
    o.x = acc[nt][0]; o.y = acc[nt][1];
    o.z = acc[nt][2]; o.w = acc[nt][3];
    *(float4*)(ob + (size_t)t * D_ + j0) = o;
  }
}

// ---------------------------------------------------------------------------
extern "C" void kernel_launch(void* const* d_in, const int* in_sizes, int n_in,
                              void* d_out, int out_size, void* d_ws,
                              size_t ws_size, hipStream_t stream) {
  const float* q = (const float*)d_in[0];
  const float* k = (const float*)d_in[1];
  const float* v = (const float*)d_in[2];
  const float* beta = (const float*)d_in[3];
  float* out = (float*)d_out;

  u16* A = (u16*)d_ws;                                    // 33.5 MB
  float* P = (float*)((char*)d_ws + 33554432);            // 1 KB
  u16* Vt = (u16*)((char*)d_ws + 33554432 + 1024);        // 16.7 MB

  ks_front9<<<dim3(BC_), dim3(1024), 0, stream>>>(k, v, beta, A, P, Vt);
  ks_scan9<<<dim3(512), dim3(256), 0, stream>>>(A, P);
  ks_output9<<<dim3(BC_), dim3(1024), 0, stream>>>(q, k, beta, A, Vt, out);
}